// Round 2
// baseline (216.985 us; speedup 1.0000x reference)
//
#include <hip/hip_runtime.h>
#include <hip/hip_bf16.h>

#define DEV __device__ __forceinline__

typedef short bf16x8 __attribute__((ext_vector_type(8)));
typedef float f32x4 __attribute__((ext_vector_type(4)));
typedef float f32x16 __attribute__((ext_vector_type(16)));
typedef unsigned int u32;
typedef unsigned int u32x4 __attribute__((ext_vector_type(4)));

constexpr int BB = 2, SS = 2048, DD = 1024, HH = 16, DHD = 64;
constexpr int MM = BB * SS; // 4096
#define QSC 0.1803368801111f  /* 0.125 * log2(e): scores in log2 domain */

#if __has_builtin(__builtin_amdgcn_exp2f)
#define EXP2(x) __builtin_amdgcn_exp2f(x)
#else
#define EXP2(x) exp2f(x)
#endif

// round-half-up bf16; bias only at exact-half cases
DEV unsigned short f2bf(float f) {
    union { float f; unsigned int u; } v; v.f = f;
    return (unsigned short)((v.u + 0x8000u) >> 16);
}
// pack two f32 -> (bf16(b)<<16)|bf16(a) : add, add, v_perm = 3 instr
#if __has_builtin(__builtin_amdgcn_perm)
DEV u32 pk2bf(float a, float b) {
    union { float f; u32 u; } ua, ub; ua.f = a; ub.f = b;
    return __builtin_amdgcn_perm(ub.u + 0x8000u, ua.u + 0x8000u, 0x07060302u);
}
#else
DEV u32 pk2bf(float a, float b) {
    union { float f; u32 u; } ua, ub; ua.f = a; ub.f = b;
    return ((ua.u + 0x8000u) >> 16) | ((ub.u + 0x8000u) & 0xffff0000u);
}
#endif

// single-instruction RNE pack (gfx950 has no builtin; inline asm per T12)
DEV u32 cvtpk2bf(float a, float b) {
    u32 r;
    asm("v_cvt_pk_bf16_f32 %0, %1, %2" : "=v"(r) : "v"(a), "v"(b));
    return r;
}

// exchange high half of a with low half of b (v_permlane32_swap_b32)
DEV void plswap(u32& a, u32& b) {
    asm("v_permlane32_swap_b32 %0, %1" : "+v"(a), "+v"(b));
}

DEV bf16x8 ld_bf16x8(const unsigned short* p) { return *(const bf16x8*)p; }

// async global->LDS, 16B per lane; lds dest = wave-uniform base + lane*16
DEV void gl16(const unsigned short* g, unsigned short* l) {
    __builtin_amdgcn_global_load_lds(
        (const __attribute__((address_space(1))) u32*)g,
        (__attribute__((address_space(3))) u32*)l, 16, 0, 0);
}

// ---- prep (fused): blocks [0,4096) = x->bf16 ; [4096,8192) = W transposes ----
__global__ void prep(const float* __restrict__ x, unsigned short* __restrict__ xb,
                     const float* __restrict__ W0, const float* __restrict__ W1,
                     const float* __restrict__ W2, const float* __restrict__ W3,
                     unsigned short* __restrict__ WtBase) {
    __shared__ float tile[32][33];
    int blk = blockIdx.x;
    if (blk < 4096) {
        int i = blk * 256 + threadIdx.x;
        float4 v = ((const float4*)x)[i];
        uint2 o;
        o.x = pk2bf(v.x, v.y);
        o.y = pk2bf(v.z, v.w);
        ((uint2*)xb)[i] = o;
        return;
    }
    blk -= 4096;                 // 4 weights x 1024 tiles
    int wsel = blk >> 10;
    const float* W = (wsel == 0) ? W0 : (wsel == 1) ? W1 : (wsel == 2) ? W2 : W3;
    unsigned short* Wt = WtBase + (size_t)wsel * DD * DD;
    int t = blk & 1023;
    int n0 = (t & 31) * 32, k0 = (t >> 5) * 32;
    int tx = threadIdx.x & 31, ty = threadIdx.x >> 5; // 32 x 8
    #pragma unroll
    for (int i = 0; i < 4; ++i)
        tile[ty + 8 * i][tx] = W[(size_t)(k0 + ty + 8 * i) * DD + n0 + tx];
    __syncthreads();
    #pragma unroll
    for (int i = 0; i < 4; ++i)
        Wt[(size_t)(n0 + ty + 8 * i) * DD + k0 + tx] = f2bf(tile[tx][ty + 8 * i]);
}

// ====================== QKV GEMM (R7 version: 128x128 tile, 16x16x32) ======================
__global__ __launch_bounds__(256) void qkv_gemm(
    const unsigned short* __restrict__ xb,
    const unsigned short* __restrict__ WtBase,
    const float* __restrict__ bq, const float* __restrict__ bk, const float* __restrict__ bv,
    unsigned short* __restrict__ Qb, unsigned short* __restrict__ Kb, unsigned short* __restrict__ Vt)
{
    __shared__ __align__(16) unsigned short Ald[2][128 * 32];
    __shared__ __align__(16) unsigned short Bld[2][128 * 32];

    const int z = blockIdx.z;
    const unsigned short* Wt = WtBase + (size_t)z * DD * DD;
    const float* bias = (z == 0) ? bq : (z == 1) ? bk : bv;

    const int m0g = blockIdx.y * 128;
    const int n0g = blockIdx.x * 128;
    const int wave = threadIdx.x >> 6, lane = threadIdx.x & 63;
    const int quad = lane >> 4, lcol = lane & 15;
    const int mb = (wave & 1) * 64, nb = (wave >> 1) * 64;

    f32x4 acc[4][4];
    #pragma unroll
    for (int i = 0; i < 4; ++i)
        #pragma unroll
        for (int j = 0; j < 4; ++j) acc[i][j] = (f32x4){0.f, 0.f, 0.f, 0.f};

    auto stage = [&](int ks, int bf) {
        #pragma unroll
        for (int i = 0; i < 4; ++i) {
            int j = wave * 4 + i;
            if (j < 8) { // A: xb rows m0g..m0g+127
                int bi = j * 64 + lane;
                int row = bi >> 2, p = (bi & 3) ^ (row & 3);
                gl16(xb + (size_t)(m0g + row) * DD + ks + p * 8, &Ald[bf][j * 512]);
            } else {     // B: Wt rows n0g..n0g+127
                int jj = j - 8;
                int bi = jj * 64 + lane;
                int row = bi >> 2, p = (bi & 3) ^ (row & 3);
                gl16(Wt + (size_t)(n0g + row) * DD + ks + p * 8, &Bld[bf][jj * 512]);
            }
        }
    };

    stage(0, 0);
    __syncthreads();

    for (int kk = 0; kk < 32; ++kk) {
        int bf = kk & 1;
        if (kk + 1 < 32) stage((kk + 1) * 32, (kk + 1) & 1);
        bf16x8 af[4], bfr[4];
        #pragma unroll
        for (int mt = 0; mt < 4; ++mt) {
            int row = mb + mt * 16 + lcol;
            af[mt] = ld_bf16x8(&Ald[bf][(row * 4 + (quad ^ (row & 3))) * 8]);
        }
        #pragma unroll
        for (int nt = 0; nt < 4; ++nt) {
            int row = nb + nt * 16 + lcol;
            bfr[nt] = ld_bf16x8(&Bld[bf][(row * 4 + (quad ^ (row & 3))) * 8]);
        }
        if (z < 2) { // transposed product: D[m=out_n][n=s]
            #pragma unroll
            for (int mt = 0; mt < 4; ++mt)
                #pragma unroll
                for (int nt = 0; nt < 4; ++nt)
                    acc[mt][nt] = __builtin_amdgcn_mfma_f32_16x16x32_bf16(bfr[nt], af[mt], acc[mt][nt], 0, 0, 0);
        } else {
            #pragma unroll
            for (int mt = 0; mt < 4; ++mt)
                #pragma unroll
                for (int nt = 0; nt < 4; ++nt)
                    acc[mt][nt] = __builtin_amdgcn_mfma_f32_16x16x32_bf16(af[mt], bfr[nt], acc[mt][nt], 0, 0, 0);
        }
        __syncthreads();
    }

    if (z < 2) {
        unsigned short* dst = (z == 0) ? Qb : Kb;
        const float sc = (z == 0) ? QSC : 1.0f;
        #pragma unroll
        for (int mt = 0; mt < 4; ++mt)
            #pragma unroll
            for (int nt = 0; nt < 4; ++nt) {
                int m = m0g + mb + mt * 16 + lcol;        // global row -> (b,s)
                int nbt = n0g + nb + nt * 16 + quad * 4;  // 4 consecutive out_n
                int b = m >> 11, s = m & (SS - 1);
                int h = nbt >> 6, dh0 = nbt & 63;
                float4 bv4 = *(const float4*)&bias[nbt];
                uint2 o;
                o.x = pk2bf((acc[mt][nt][0] + bv4.x) * sc, (acc[mt][nt][1] + bv4.y) * sc);
                o.y = pk2bf((acc[mt][nt][2] + bv4.z) * sc, (acc[mt][nt][3] + bv4.w) * sc);
                *(uint2*)&dst[(((size_t)b * HH + h) * SS + s) * DHD + dh0] = o;
            }
    } else {
        #pragma unroll
        for (int mt = 0; mt < 4; ++mt)
            #pragma unroll
            for (int nt = 0; nt < 4; ++nt) {
                int n = n0g + nb + nt * 16 + lcol;        // out_n
                int mbt = m0g + mb + mt * 16 + quad * 4;  // 4 consecutive global rows
                int h = n >> 6, dh = n & 63;
                int b = mbt >> 11, s0 = mbt & (SS - 1);
                float bvv = bias[n];
                uint2 o;
                o.x = pk2bf(acc[mt][nt][0] + bvv, acc[mt][nt][1] + bvv);
                o.y = pk2bf(acc[mt][nt][2] + bvv, acc[mt][nt][3] + bvv);
                *(uint2*)&Vt[(((size_t)b * HH + h) * DHD + dh) * SS + s0] = o;
            }
    }
}

// ====================== attention v9: 32x32 MFMA + key-split wave pairs ======================
// 8 waves = 4 qgroups (32 q-rows each) x 2 key-halves (32 keys each of the 64-key chunk).
// Q register-resident (4 B-frags). QK = 4 ds_read + 4 MFMA(32x32x16); softmax P
// redistributed to the PV A-frag layout IN-REGISTER via 8 cvt_pk + 4 permlane32_swap
// (no tb LDS round trip). PV = 4 ds_read + 4 MFMA. LDS ops/wave/chunk: ~10 vs v7's ~22.
// Staging scheme/swizzle/double-buffer identical to v7 (measured 0 conflicts).
__global__ __launch_bounds__(512, 4) void attn(
    const unsigned short* __restrict__ Qb,
    const unsigned short* __restrict__ Kb,
    const unsigned short* __restrict__ Vt,
    unsigned short* __restrict__ Ob)
{
    // [buf][0]=K (keys x dh, swizzled), [buf][1]=V (dh x keys, swizzled). 32 KB.
    __shared__ __align__(16) unsigned short smem[2][2][64 * 64];
    __shared__ float psw[8][32];
    __shared__ float smax[8];

    const int g = blockIdx.y * gridDim.x + blockIdx.x;  // grid (16, 32) = 512
    const int bh = (g & 7) * 4 + ((g >> 3) & 3);        // fixed g%32 per bh -> fixed XCD
    const int qt = g >> 5;                               // 0..15
    const int b = bh >> 4, h = bh & (HH - 1);
    const unsigned short* Qbh = Qb + (size_t)bh * SS * DHD;
    const unsigned short* Kbh = Kb + (size_t)bh * SS * DHD;
    const unsigned short* Vbh = Vt + (size_t)bh * DHD * SS;

    const int wave = threadIdx.x >> 6, lane = threadIdx.x & 63;
    const int l31 = lane & 31, lh = lane >> 5;
    const int qg = wave >> 1, khalf = wave & 1;
    const int rowbase = qt * 128 + qg * 32;
    const int krow = khalf * 32 + l31;                  // this wave's key rows in Kld

    // Q B-frags: qf[ks] holds Q[rowbase+l31][ks*16 + lh*8 .. +8]  (n=qrow, k=dh)
    bf16x8 qf[4];
    #pragma unroll
    for (int ks = 0; ks < 4; ++ks)
        qf[ks] = ld_bf16x8(Qbh + (size_t)(rowbase + l31) * DHD + ks * 16 + lh * 8);

    auto stage = [&](int c, int bf) {
        int kb = c * 64;
        #pragma unroll
        for (int i = 0; i < 2; ++i) {
            int j = wave * 2 + i;
            if (j < 8) { // K: rows = keys, 8 parts of dh
                int bi = j * 64 + lane;
                int r = bi >> 3, p = (bi & 7) ^ (r & 7);
                gl16(Kbh + (size_t)(kb + r) * DHD + p * 8, &smem[bf][0][j * 512]);
            } else {     // V: rows = dh, 8 parts of keys
                int jj = j - 8;
                int bi = jj * 64 + lane;
                int dh = bi >> 3, p = (bi & 7) ^ (dh & 7);
                gl16(Vbh + (size_t)dh * SS + kb + p * 8, &smem[bf][1][jj * 512]);
            }
        }
    };

    // ---- prologue: stage chunk 0, block-uniform m0 estimate from it ----
    stage(0, 0);
    __syncthreads();
    {
        f32x16 a0;
        #pragma unroll
        for (int i = 0; i < 16; ++i) a0[i] = 0.f;
        #pragma unroll
        for (int ks = 0; ks < 4; ++ks) {
            int p = ks * 2 + lh;
            bf16x8 ka = ld_bf16x8(&smem[0][0][(krow * 8 + (p ^ (krow & 7))) * 8]);
            a0 = __builtin_amdgcn_mfma_f32_32x32x16_bf16(ka, qf[ks], a0, 0, 0, 0);
        }
        float m0 = -1e30f;
        #pragma unroll
        for (int i = 0; i < 16; ++i) m0 = fmaxf(m0, a0[i]);
        #pragma unroll
        for (int msk = 1; msk < 64; msk <<= 1) m0 = fmaxf(m0, __shfl_xor(m0, msk, 64));
        if (lane == 0) smax[wave] = m0;
    }
    __syncthreads();
    float m0b = smax[0];
    #pragma unroll
    for (int w2 = 1; w2 < 8; ++w2) m0b = fmaxf(m0b, smax[w2]);
    const float nm0 = -m0b;

    // ---- main loop over 32 chunks of 64 keys (wave handles its 32-key half) ----
    f32x16 oacc[2];
    #pragma unroll
    for (int db = 0; db < 2; ++db)
        #pragma unroll
        for (int i = 0; i < 16; ++i) oacc[db][i] = 0.f;
    float ps = 0.f;

    for (int c = 0; c < 32; ++c) {
        int bf = c & 1;
        if (c + 1 < 32) stage(c + 1, (c + 1) & 1);

        // QK: D[key=row][qrow=col], C-init = -m0
        f32x16 s;
        #pragma unroll
        for (int i = 0; i < 16; ++i) s[i] = nm0;
        __builtin_amdgcn_s_setprio(1);
        #pragma unroll
        for (int ks = 0; ks < 4; ++ks) {
            int p = ks * 2 + lh;
            bf16x8 ka = ld_bf16x8(&smem[bf][0][(krow * 8 + (p ^ (krow & 7))) * 8]);
            s = __builtin_amdgcn_mfma_f32_32x32x16_bf16(ka, qf[ks], s, 0, 0, 0);
        }
        __builtin_amdgcn_s_setprio(0);

        // softmax: exp2, row-sum, pack to bf16, permlane-swap into PV A-frag layout
        u32 w[8];
        float psl = 0.f;
        #pragma unroll
        for (int i = 0; i < 8; ++i) {
            float ea = EXP2(s[2 * i]), eb = EXP2(s[2 * i + 1]);
            psl += ea + eb;
            w[i] = cvtpk2bf(ea, eb);
        }
        ps += psl;
        plswap(w[0], w[2]); plswap(w[1], w[3]);
        plswap(w[4], w[6]); plswap(w[5], w[7]);
        union { u32x4 u; bf16x8 hv; } pa0, pa1;
        pa0.u = (u32x4){w[0], w[1], w[2], w[3]};   // local keys 0..15
        pa1.u = (u32x4){w[4], w[5], w[6], w[7]};   // local keys 16..31

        // PV: A = P (regs), B = V frags; keys = khalf*32 + ks2*16 + ...
        __builtin_amdgcn_s_setprio(1);
        #pragma unroll
        for (int db = 0; db < 2; ++db) {
            int dh = db * 32 + l31;
            #pragma unroll
            for (int ks2 = 0; ks2 < 2; ++ks2) {
                int p = khalf * 4 + ks2 * 2 + lh;
                bf16x8 vb = ld_bf16x8(&smem[bf][1][(dh * 8 + (p ^ (dh & 7))) * 8]);
                oacc[db] = __builtin_amdgcn_mfma_f32_32x32x16_bf16(
                    ks2 ? pa1.hv : pa0.hv, vb, oacc[db], 0, 0, 0);
            }
        }
        __builtin_amdgcn_s_setprio(0);
        __syncthreads();
    }

    // ---- epilogue: wave-pair combine (key halves), normalize, write ----
    // wave writes its "other" dh-block for its partner; keeps dh-block = khalf.
    float* exch = (float*)smem;            // [8][32*32] f32 = 32 KB (K/V dead now)
    {
        int other = khalf ^ 1;
        #pragma unroll
        for (int r = 0; r < 16; ++r) {
            int q = (r & 3) + 8 * (r >> 2) + 4 * lh;
            exch[wave * 1024 + q * 32 + l31] = oacc[other][r];
        }
        float ps2 = ps + __shfl_xor(ps, 32, 64);   // row-total over this wave's keys
        if (lane < 32) psw[wave][lane] = ps2;
    }
    __syncthreads();
    {
        const float* po = &exch[(wave ^ 1) * 1024];
        int dh = khalf * 32 + l31;
        #pragma unroll
        for (int r = 0; r < 16; ++r) {
            int q = (r & 3) + 8 * (r >> 2) + 4 * lh;
            float v = oacc[khalf][r] + po[q * 32 + l31];
            float pst = psw[qg * 2][q] + psw[qg * 2 + 1][q];
            int srow = rowbase + q;
            Ob[(((size_t)b * SS + srow) * HH + h) * DHD + dh] = f2bf(v / pst);
        }
    }
}

// ====================== output GEMM v2 ======================
// Tile 64 tokens x 128 out_n, BK=64 dbuf (16 barriers), transposed product:
// A = Wto (rows = out_n), B = Ob (rows = tokens) -> D[m=out_n][n=token];
// reg-quad r gives 4 consecutive out_n -> float4 stores (8 per thread).
// LDS frag swizzle = attn Kld 8-part scheme (measured 0 conflicts).
__global__ __launch_bounds__(256) void out_gemm(
    const unsigned short* __restrict__ Ob,
    const unsigned short* __restrict__ Wto,
    const float* __restrict__ bo,
    float* __restrict__ out)
{
    __shared__ __align__(16) unsigned short Wld[2][128 * 64]; // out_n x k
    __shared__ __align__(16) unsigned short Old[2][64 * 64];  // token x k

    const int m0g = blockIdx.y * 64;    // tokens
    const int n0g = blockIdx.x * 128;   // out_n
    const int wave = threadIdx.x >> 6, lane = threadIdx.x & 63;
    const int quad = lane >> 4, lcol = lane & 15;
    const int nb = wave * 32;           // wave's out_n sub-range

    f32x4 acc[2][4];
    #pragma unroll
    for (int i = 0; i < 2; ++i)
        #pragma unroll
        for (int j = 0; j < 4; ++j) acc[i][j] = (f32x4){0.f, 0.f, 0.f, 0.f};

    auto stage = [&](int ks, int bf) {
        #pragma unroll
        for (int i = 0; i < 6; ++i) {
            int j = wave * 6 + i;
            if (j < 16) { // W: 128 rows x 8 parts
                int bi = j * 64 + lane;
                int r = bi >> 3, p = (bi & 7) ^ (r & 7);
                gl16(Wto + (size_t)(n0g + r) * DD + ks + p * 8, &Wld[bf][j * 512]);
            } else {      // Ob: 64 rows x 8 parts
                int jj = j - 16;
                int bi = jj * 64 + lane;
                int r = bi >> 3, p = (bi & 7) ^ (r & 7);
                gl16(Ob + (size_t)(m0g + r) * DD + ks + p * 8, &Old[bf][jj * 512]);
            }
        }
    };

    stage(0, 0);
    __syncthreads();

    for (int kk = 0; kk < 16; ++kk) {
        int bf = kk & 1;
        if (kk + 1 < 16) stage((kk + 1) * 64, (kk + 1) & 1);
        #pragma unroll
        for (int kh = 0; kh < 2; ++kh) {
            bf16x8 wf[2], of[4];
            #pragma unroll
            for (int i = 0; i < 2; ++i) {
                int row = nb + i * 16 + lcol;
                wf[i] = ld_bf16x8(&Wld[bf][(row * 8 + ((kh * 4 + quad) ^ (row & 7))) * 8]);
            }
            #pragma unroll
            for (int j = 0; j < 4; ++j) {
                int row = j * 16 + lcol;
                of[j] = ld_bf16x8(&Old[bf][(row * 8 + ((kh * 4 + quad) ^ (row & 7))) * 8]);
            }
            #pragma unroll
            for (int i = 0; i < 2; ++i)
                #pragma unroll
                for (int j = 0; j < 4; ++j)
                    acc[i][j] = __builtin_amdgcn_mfma_f32_16x16x32_bf16(wf[i], of[j], acc[i][j], 0, 0, 0);
        }
        __syncthreads();
    }

    // C: col = token (lcol within j-tile), row = out_n (quad*4 + r, consecutive)
    #pragma unroll
    for (int i = 0; i < 2; ++i) {
        int n4 = n0g + nb + i * 16 + quad * 4;
        float4 bv4 = *(const float4*)&bo[n4];
        #pragma unroll
        for (int j = 0; j < 4; ++j) {
            int token = m0g + j * 16 + lcol;
            float4 o;
            o.x = acc[i][j][0] + bv4.x;
            o.y = acc[i][j][1] + bv4.y;
            o.z = acc[i][j][2] + bv4.z;
            o.w = acc[i][j][3] + bv4.w;
            *(float4*)&out[(size_t)token * DD + n4] = o;
        }
    }
}

extern "C" void kernel_launch(void* const* d_in, const int* in_sizes, int n_in,
                              void* d_out, int out_size, void* d_ws, size_t ws_size,
                              hipStream_t stream)
{
    const float* x  = (const float*)d_in[0];
    const float* Wq = (const float*)d_in[1];
    const float* bq = (const float*)d_in[2];
    const float* Wk = (const float*)d_in[3];
    const float* bk = (const float*)d_in[4];
    const float* Wv = (const float*)d_in[5];
    const float* bv = (const float*)d_in[6];
    const float* Wo = (const float*)d_in[7];
    const float* bo = (const float*)d_in[8];
    float* out = (float*)d_out;

    unsigned short* ws = (unsigned short*)d_ws;
    unsigned short* Wt  = ws;                        // 4 * D*D (q,k,v,o)
    unsigned short* Wto = Wt + 3 * (size_t)DD * DD;
    unsigned short* Qb  = Wt + 4 * (size_t)DD * DD;  // M*D each
    unsigned short* Kb  = Qb + (size_t)MM * DD;
    unsigned short* Vt  = Kb + (size_t)MM * DD;
    unsigned short* xb  = Vt + (size_t)MM * DD;      // total 40 MB
    unsigned short* Ob  = xb;                        // alias: xb dead after qkv_gemm

    prep<<<8192, 256, 0, stream>>>(x, xb, Wq, Wk, Wv, Wo, Wt);

    qkv_gemm<<<dim3(DD / 128, MM / 128, 3), 256, 0, stream>>>(xb, Wt, bq, bk, bv, Qb, Kb, Vt);

    attn<<<dim3(16, 32), 512, 0, stream>>>(Qb, Kb, Vt, Ob);

    out_gemm<<<dim3(DD / 128, MM / 64), 256, 0, stream>>>(Ob, Wto, bo, out);
}

// Round 3
// 197.304 us; speedup vs baseline: 1.0998x; 1.0998x over previous
//
#include <hip/hip_runtime.h>
#include <hip/hip_bf16.h>

#define DEV __device__ __forceinline__

typedef short bf16x8 __attribute__((ext_vector_type(8)));
typedef float f32x4 __attribute__((ext_vector_type(4)));
typedef unsigned int u32;
typedef unsigned int u32x4 __attribute__((ext_vector_type(4)));

constexpr int BB = 2, SS = 2048, DD = 1024, HH = 16, DHD = 64;
constexpr int MM = BB * SS; // 4096
#define QSC 0.1803368801111f  /* 0.125 * log2(e): scores in log2 domain */

#if __has_builtin(__builtin_amdgcn_exp2f)
#define EXP2(x) __builtin_amdgcn_exp2f(x)
#else
#define EXP2(x) exp2f(x)
#endif

// round-half-up bf16; bias only at exact-half cases
DEV unsigned short f2bf(float f) {
    union { float f; unsigned int u; } v; v.f = f;
    return (unsigned short)((v.u + 0x8000u) >> 16);
}
// pack two f32 -> (bf16(b)<<16)|bf16(a) : add, add, v_perm = 3 instr
#if __has_builtin(__builtin_amdgcn_perm)
DEV u32 pk2bf(float a, float b) {
    union { float f; u32 u; } ua, ub; ua.f = a; ub.f = b;
    return __builtin_amdgcn_perm(ub.u + 0x8000u, ua.u + 0x8000u, 0x07060302u);
}
#else
DEV u32 pk2bf(float a, float b) {
    union { float f; u32 u; } ua, ub; ua.f = a; ub.f = b;
    return ((ua.u + 0x8000u) >> 16) | ((ub.u + 0x8000u) & 0xffff0000u);
}
#endif

// single-instruction RNE pack (gfx950 has no builtin; inline asm per T12)
DEV u32 cvtpk2bf(float a, float b) {
    u32 r;
    asm("v_cvt_pk_bf16_f32 %0, %1, %2" : "=v"(r) : "v"(a), "v"(b));
    return r;
}

DEV bf16x8 ld_bf16x8(const unsigned short* p) { return *(const bf16x8*)p; }

// async global->LDS, 16B per lane; lds dest = wave-uniform base + lane*16
DEV void gl16(const unsigned short* g, unsigned short* l) {
    __builtin_amdgcn_global_load_lds(
        (const __attribute__((address_space(1))) u32*)g,
        (__attribute__((address_space(3))) u32*)l, 16, 0, 0);
}

// ---- prep (fused): blocks [0,4096) = x->bf16 ; [4096,8192) = W transposes ----
__global__ void prep(const float* __restrict__ x, unsigned short* __restrict__ xb,
                     const float* __restrict__ W0, const float* __restrict__ W1,
                     const float* __restrict__ W2, const float* __restrict__ W3,
                     unsigned short* __restrict__ WtBase) {
    __shared__ float tile[32][33];
    int blk = blockIdx.x;
    if (blk < 4096) {
        int i = blk * 256 + threadIdx.x;
        float4 v = ((const float4*)x)[i];
        uint2 o;
        o.x = pk2bf(v.x, v.y);
        o.y = pk2bf(v.z, v.w);
        ((uint2*)xb)[i] = o;
        return;
    }
    blk -= 4096;                 // 4 weights x 1024 tiles
    int wsel = blk >> 10;
    const float* W = (wsel == 0) ? W0 : (wsel == 1) ? W1 : (wsel == 2) ? W2 : W3;
    unsigned short* Wt = WtBase + (size_t)wsel * DD * DD;
    int t = blk & 1023;
    int n0 = (t & 31) * 32, k0 = (t >> 5) * 32;
    int tx = threadIdx.x & 31, ty = threadIdx.x >> 5; // 32 x 8
    #pragma unroll
    for (int i = 0; i < 4; ++i)
        tile[ty + 8 * i][tx] = W[(size_t)(k0 + ty + 8 * i) * DD + n0 + tx];
    __syncthreads();
    #pragma unroll
    for (int i = 0; i < 4; ++i)
        Wt[(size_t)(n0 + ty + 8 * i) * DD + k0 + tx] = f2bf(tile[tx][ty + 8 * i]);
}

// ====================== QKV GEMM (R7 version: 128x128 tile, 16x16x32) ======================
__global__ __launch_bounds__(256) void qkv_gemm(
    const unsigned short* __restrict__ xb,
    const unsigned short* __restrict__ WtBase,
    const float* __restrict__ bq, const float* __restrict__ bk, const float* __restrict__ bv,
    unsigned short* __restrict__ Qb, unsigned short* __restrict__ Kb, unsigned short* __restrict__ Vt)
{
    __shared__ __align__(16) unsigned short Ald[2][128 * 32];
    __shared__ __align__(16) unsigned short Bld[2][128 * 32];

    const int z = blockIdx.z;
    const unsigned short* Wt = WtBase + (size_t)z * DD * DD;
    const float* bias = (z == 0) ? bq : (z == 1) ? bk : bv;

    const int m0g = blockIdx.y * 128;
    const int n0g = blockIdx.x * 128;
    const int wave = threadIdx.x >> 6, lane = threadIdx.x & 63;
    const int quad = lane >> 4, lcol = lane & 15;
    const int mb = (wave & 1) * 64, nb = (wave >> 1) * 64;

    f32x4 acc[4][4];
    #pragma unroll
    for (int i = 0; i < 4; ++i)
        #pragma unroll
        for (int j = 0; j < 4; ++j) acc[i][j] = (f32x4){0.f, 0.f, 0.f, 0.f};

    auto stage = [&](int ks, int bf) {
        #pragma unroll
        for (int i = 0; i < 4; ++i) {
            int j = wave * 4 + i;
            if (j < 8) { // A: xb rows m0g..m0g+127
                int bi = j * 64 + lane;
                int row = bi >> 2, p = (bi & 3) ^ (row & 3);
                gl16(xb + (size_t)(m0g + row) * DD + ks + p * 8, &Ald[bf][j * 512]);
            } else {     // B: Wt rows n0g..n0g+127
                int jj = j - 8;
                int bi = jj * 64 + lane;
                int row = bi >> 2, p = (bi & 3) ^ (row & 3);
                gl16(Wt + (size_t)(n0g + row) * DD + ks + p * 8, &Bld[bf][jj * 512]);
            }
        }
    };

    stage(0, 0);
    __syncthreads();

    for (int kk = 0; kk < 32; ++kk) {
        int bf = kk & 1;
        if (kk + 1 < 32) stage((kk + 1) * 32, (kk + 1) & 1);
        bf16x8 af[4], bfr[4];
        #pragma unroll
        for (int mt = 0; mt < 4; ++mt) {
            int row = mb + mt * 16 + lcol;
            af[mt] = ld_bf16x8(&Ald[bf][(row * 4 + (quad ^ (row & 3))) * 8]);
        }
        #pragma unroll
        for (int nt = 0; nt < 4; ++nt) {
            int row = nb + nt * 16 + lcol;
            bfr[nt] = ld_bf16x8(&Bld[bf][(row * 4 + (quad ^ (row & 3))) * 8]);
        }
        if (z < 2) { // transposed product: D[m=out_n][n=s]
            #pragma unroll
            for (int mt = 0; mt < 4; ++mt)
                #pragma unroll
                for (int nt = 0; nt < 4; ++nt)
                    acc[mt][nt] = __builtin_amdgcn_mfma_f32_16x16x32_bf16(bfr[nt], af[mt], acc[mt][nt], 0, 0, 0);
        } else {
            #pragma unroll
            for (int mt = 0; mt < 4; ++mt)
                #pragma unroll
                for (int nt = 0; nt < 4; ++nt)
                    acc[mt][nt] = __builtin_amdgcn_mfma_f32_16x16x32_bf16(af[mt], bfr[nt], acc[mt][nt], 0, 0, 0);
        }
        __syncthreads();
    }

    if (z < 2) {
        unsigned short* dst = (z == 0) ? Qb : Kb;
        const float sc = (z == 0) ? QSC : 1.0f;
        #pragma unroll
        for (int mt = 0; mt < 4; ++mt)
            #pragma unroll
            for (int nt = 0; nt < 4; ++nt) {
                int m = m0g + mb + mt * 16 + lcol;        // global row -> (b,s)
                int nbt = n0g + nb + nt * 16 + quad * 4;  // 4 consecutive out_n
                int b = m >> 11, s = m & (SS - 1);
                int h = nbt >> 6, dh0 = nbt & 63;
                float4 bv4 = *(const float4*)&bias[nbt];
                uint2 o;
                o.x = pk2bf((acc[mt][nt][0] + bv4.x) * sc, (acc[mt][nt][1] + bv4.y) * sc);
                o.y = pk2bf((acc[mt][nt][2] + bv4.z) * sc, (acc[mt][nt][3] + bv4.w) * sc);
                *(uint2*)&dst[(((size_t)b * HH + h) * SS + s) * DHD + dh0] = o;
            }
    } else {
        #pragma unroll
        for (int mt = 0; mt < 4; ++mt)
            #pragma unroll
            for (int nt = 0; nt < 4; ++nt) {
                int n = n0g + nb + nt * 16 + lcol;        // out_n
                int mbt = m0g + mb + mt * 16 + quad * 4;  // 4 consecutive global rows
                int h = n >> 6, dh = n & 63;
                int b = mbt >> 11, s0 = mbt & (SS - 1);
                float bvv = bias[n];
                uint2 o;
                o.x = pk2bf(acc[mt][nt][0] + bvv, acc[mt][nt][1] + bvv);
                o.y = pk2bf(acc[mt][nt][2] + bvv, acc[mt][nt][3] + bvv);
                *(uint2*)&Vt[(((size_t)b * HH + h) * DHD + dh) * SS + s0] = o;
            }
    }
}

// ====================== attention v10: v7 + P-in-register (tb eliminated) ======================
// Identical to v7 (58.5us, 0 conflicts) except: QK loads K-rows in the permuted
// order kr = kf2*32 + 8*(lcol>>2) + 4*j + (lcol&3), so the S-output regs of MFMA
// pair j=0,1 concatenate into the PV A-fragment (keys 8*quad..8*quad+7) directly
// in registers (2x v_cvt_pk_bf16_f32 each). tb LDS round-trip (4 ds_write_b64 +
// 2 ds_read_b128 per wave-chunk) deleted: DS-pipe cycles 256 -> ~208 per chunk.
// Kld swizzle updated to swz(r) = (r&3)|((r>>3)&1)<<2 (row bits 0,1,3) so the
// permuted read groups stay 2-way bank-aliased (free). PV/Vld/epilogue unchanged.
__global__ __launch_bounds__(512, 4) void attn(
    const unsigned short* __restrict__ Qb,
    const unsigned short* __restrict__ Kb,
    const unsigned short* __restrict__ Vt,
    unsigned short* __restrict__ Ob)
{
    __shared__ __align__(16) unsigned short Kld[2][64 * 64]; // keys x dh, swz(r)-swizzled blocks
    __shared__ __align__(16) unsigned short Vld[2][64 * 64]; // dh x keys, (dh&7)-swizzled blocks

    const int g = blockIdx.y * gridDim.x + blockIdx.x;  // grid (16, 32) = 512
    const int bh = (g & 7) * 4 + ((g >> 3) & 3);        // fixed g%32 per bh -> fixed XCD
    const int qt = g >> 5;                               // 0..15
    const int b = bh >> 4, h = bh & (HH - 1);
    const unsigned short* Qbh = Qb + (size_t)bh * SS * DHD;
    const unsigned short* Kbh = Kb + (size_t)bh * SS * DHD;
    const unsigned short* Vbh = Vt + (size_t)bh * DHD * SS;

    const int wave = threadIdx.x >> 6, lane = threadIdx.x & 63;
    const int quad = lane >> 4, lcol = lane & 15;
    const int rowbase = qt * 128 + wave * 16;

    // Q B-frags (n = q-row, k = dh); 0.125*log2e folded into Q
    bf16x8 qf0 = ld_bf16x8(Qbh + (size_t)(rowbase + lcol) * DHD + quad * 8);
    bf16x8 qf1 = ld_bf16x8(Qbh + (size_t)(rowbase + lcol) * DHD + 32 + quad * 8);

    // K-row this lane reads for QK MFMA-pair (kf2, j): keys 8q+4j+r land in regs
    auto krow = [&](int kf2, int j) {
        return kf2 * 32 + ((lcol >> 2) << 3) + j * 4 + (lcol & 3);
    };
    auto kswz = [](int r) { return (r & 3) | (((r >> 3) & 1) << 2); };

    auto stage = [&](int c, int bf) {
        int kb = c * 64;
        #pragma unroll
        for (int i = 0; i < 2; ++i) {
            int j = wave * 2 + i;
            if (j < 8) { // K: rows = keys, 8 parts of dh, swz(r) slot permutation
                int bi = j * 64 + lane;
                int r = bi >> 3, p = (bi & 7) ^ ((r & 3) | (((r >> 3) & 1) << 2));
                gl16(Kbh + (size_t)(kb + r) * DHD + p * 8, &Kld[bf][j * 512]);
            } else {     // V: rows = dh, 8 parts of keys
                int jj = j - 8;
                int bi = jj * 64 + lane;
                int dh = bi >> 3, p = (bi & 7) ^ (dh & 7);
                gl16(Vbh + (size_t)dh * SS + kb + p * 8, &Vld[bf][jj * 512]);
            }
        }
    };

    // ---- prologue: stage chunk 0, wave-uniform m0 estimate from it ----
    stage(0, 0);
    __syncthreads();

    float m0 = -1e30f;
    #pragma unroll
    for (int kf2 = 0; kf2 < 2; ++kf2)
        #pragma unroll
        for (int j = 0; j < 2; ++j) {
            int kr = krow(kf2, j), sw = kswz(kr);
            bf16x8 ka0 = ld_bf16x8(&Kld[0][(kr * 8 + (quad ^ sw)) * 8]);
            bf16x8 ka1 = ld_bf16x8(&Kld[0][(kr * 8 + ((quad + 4) ^ sw)) * 8]);
            f32x4 s = (f32x4){0.f, 0.f, 0.f, 0.f};
            s = __builtin_amdgcn_mfma_f32_16x16x32_bf16(ka0, qf0, s, 0, 0, 0);
            s = __builtin_amdgcn_mfma_f32_16x16x32_bf16(ka1, qf1, s, 0, 0, 0);
            #pragma unroll
            for (int r = 0; r < 4; ++r) m0 = fmaxf(m0, s[r]);
        }
    #pragma unroll
    for (int msk = 1; msk < 64; msk <<= 1) m0 = fmaxf(m0, __shfl_xor(m0, msk, 64));
    const f32x4 minit = (f32x4){-m0, -m0, -m0, -m0};

    // ---- main loop over 32 chunks of 64 keys ----
    f32x4 oacc[4];
    #pragma unroll
    for (int nt = 0; nt < 4; ++nt) oacc[nt] = (f32x4){0.f, 0.f, 0.f, 0.f};
    float ps = 0.f;

    for (int c = 0; c < 32; ++c) {
        int bf = c & 1;
        if (c + 1 < 32) stage(c + 1, (c + 1) & 1);

        // S^T = K.Q^T (C-init = -m0) -> exp2 -> pack into PV A-frags (registers)
        bf16x8 paf[2];
        #pragma unroll
        for (int kf2 = 0; kf2 < 2; ++kf2) {
            u32 w[4];
            #pragma unroll
            for (int j = 0; j < 2; ++j) {
                int kr = krow(kf2, j), sw = kswz(kr);
                bf16x8 ka0 = ld_bf16x8(&Kld[bf][(kr * 8 + (quad ^ sw)) * 8]);
                bf16x8 ka1 = ld_bf16x8(&Kld[bf][(kr * 8 + ((quad + 4) ^ sw)) * 8]);
                f32x4 s = minit;
                s = __builtin_amdgcn_mfma_f32_16x16x32_bf16(ka0, qf0, s, 0, 0, 0);
                s = __builtin_amdgcn_mfma_f32_16x16x32_bf16(ka1, qf1, s, 0, 0, 0);
                float e0 = EXP2(s[0]), e1 = EXP2(s[1]);
                float e2 = EXP2(s[2]), e3 = EXP2(s[3]);
                ps += (e0 + e1) + (e2 + e3);
                w[j * 2]     = cvtpk2bf(e0, e1);
                w[j * 2 + 1] = cvtpk2bf(e2, e3);
            }
            union { u32x4 u; bf16x8 v; } pu;
            pu.u = (u32x4){w[0], w[1], w[2], w[3]};
            paf[kf2] = pu.v;
        }

        // PV: A = P (registers), B = V (from Vld) — identical to v7 reads
        #pragma unroll
        for (int kf2 = 0; kf2 < 2; ++kf2) {
            #pragma unroll
            for (int nt = 0; nt < 4; ++nt) {
                int dh = nt * 16 + lcol;
                bf16x8 vb = ld_bf16x8(&Vld[bf][(dh * 8 + ((kf2 * 4 + quad) ^ (dh & 7))) * 8]);
                oacc[nt] = __builtin_amdgcn_mfma_f32_16x16x32_bf16(paf[kf2], vb, oacc[nt], 0, 0, 0);
            }
        }
        __syncthreads();
    }

    // ---- epilogue: per-row normalize (rows owned entirely by this wave) ----
    ps += __shfl_xor(ps, 16, 64);
    ps += __shfl_xor(ps, 32, 64);
    float inv = 1.0f / ps;   // valid at lanes where lcol == q-row
    #pragma unroll
    for (int r = 0; r < 4; ++r) {
        float iv = __shfl(inv, quad * 4 + r, 64);
        int srow = rowbase + quad * 4 + r;
        size_t base = (((size_t)b * SS + srow) * HH + h) * DHD;
        #pragma unroll
        for (int nt = 0; nt < 4; ++nt)
            Ob[base + nt * 16 + lcol] = f2bf(oacc[nt][r] * iv);
    }
}

// ====================== output GEMM v2 ======================
// Tile 64 tokens x 128 out_n, BK=64 dbuf (16 barriers), transposed product:
// A = Wto (rows = out_n), B = Ob (rows = tokens) -> D[m=out_n][n=token];
// reg-quad r gives 4 consecutive out_n -> float4 stores (8 per thread).
// LDS frag swizzle = attn Kld 8-part scheme (measured 0 conflicts).
__global__ __launch_bounds__(256) void out_gemm(
    const unsigned short* __restrict__ Ob,
    const unsigned short* __restrict__ Wto,
    const float* __restrict__ bo,
    float* __restrict__ out)
{
    __shared__ __align__(16) unsigned short Wld[2][128 * 64]; // out_n x k
    __shared__ __align__(16) unsigned short Old[2][64 * 64];  // token x k

    const int m0g = blockIdx.y * 64;    // tokens
    const int n0g = blockIdx.x * 128;   // out_n
    const int wave = threadIdx.x >> 6, lane = threadIdx.x & 63;
    const int quad = lane >> 4, lcol = lane & 15;
    const int nb = wave * 32;           // wave's out_n sub-range

    f32x4 acc[2][4];
    #pragma unroll
    for (int i = 0; i < 2; ++i)
        #pragma unroll
        for (int j = 0; j < 4; ++j) acc[i][j] = (f32x4){0.f, 0.f, 0.f, 0.f};

    auto stage = [&](int ks, int bf) {
        #pragma unroll
        for (int i = 0; i < 6; ++i) {
            int j = wave * 6 + i;
            if (j < 16) { // W: 128 rows x 8 parts
                int bi = j * 64 + lane;
                int r = bi >> 3, p = (bi & 7) ^ (r & 7);
                gl16(Wto + (size_t)(n0g + r) * DD + ks + p * 8, &Wld[bf][j * 512]);
            } else {      // Ob: 64 rows x 8 parts
                int jj = j - 16;
                int bi = jj * 64 + lane;
                int r = bi >> 3, p = (bi & 7) ^ (r & 7);
                gl16(Ob + (size_t)(m0g + r) * DD + ks + p * 8, &Old[bf][jj * 512]);
            }
        }
    };

    stage(0, 0);
    __syncthreads();

    for (int kk = 0; kk < 16; ++kk) {
        int bf = kk & 1;
        if (kk + 1 < 16) stage((kk + 1) * 64, (kk + 1) & 1);
        #pragma unroll
        for (int kh = 0; kh < 2; ++kh) {
            bf16x8 wf[2], of[4];
            #pragma unroll
            for (int i = 0; i < 2; ++i) {
                int row = nb + i * 16 + lcol;
                wf[i] = ld_bf16x8(&Wld[bf][(row * 8 + ((kh * 4 + quad) ^ (row & 7))) * 8]);
            }
            #pragma unroll
            for (int j = 0; j < 4; ++j) {
                int row = j * 16 + lcol;
                of[j] = ld_bf16x8(&Old[bf][(row * 8 + ((kh * 4 + quad) ^ (row & 7))) * 8]);
            }
            #pragma unroll
            for (int i = 0; i < 2; ++i)
                #pragma unroll
                for (int j = 0; j < 4; ++j)
                    acc[i][j] = __builtin_amdgcn_mfma_f32_16x16x32_bf16(wf[i], of[j], acc[i][j], 0, 0, 0);
        }
        __syncthreads();
    }

    // C: col = token (lcol within j-tile), row = out_n (quad*4 + r, consecutive)
    #pragma unroll
    for (int i = 0; i < 2; ++i) {
        int n4 = n0g + nb + i * 16 + quad * 4;
        float4 bv4 = *(const float4*)&bo[n4];
        #pragma unroll
        for (int j = 0; j < 4; ++j) {
            int token = m0g + j * 16 + lcol;
            float4 o;
            o.x = acc[i][j][0] + bv4.x;
            o.y = acc[i][j][1] + bv4.y;
            o.z = acc[i][j][2] + bv4.z;
            o.w = acc[i][j][3] + bv4.w;
            *(float4*)&out[(size_t)token * DD + n4] = o;
        }
    }
}

extern "C" void kernel_launch(void* const* d_in, const int* in_sizes, int n_in,
                              void* d_out, int out_size, void* d_ws, size_t ws_size,
                              hipStream_t stream)
{
    const float* x  = (const float*)d_in[0];
    const float* Wq = (const float*)d_in[1];
    const float* bq = (const float*)d_in[2];
    const float* Wk = (const float*)d_in[3];
    const float* bk = (const float*)d_in[4];
    const float* Wv = (const float*)d_in[5];
    const float* bv = (const float*)d_in[6];
    const float* Wo = (const float*)d_in[7];
    const float* bo = (const float*)d_in[8];
    float* out = (float*)d_out;

    unsigned short* ws = (unsigned short*)d_ws;
    unsigned short* Wt  = ws;                        // 4 * D*D (q,k,v,o)
    unsigned short* Wto = Wt + 3 * (size_t)DD * DD;
    unsigned short* Qb  = Wt + 4 * (size_t)DD * DD;  // M*D each
    unsigned short* Kb  = Qb + (size_t)MM * DD;
    unsigned short* Vt  = Kb + (size_t)MM * DD;
    unsigned short* xb  = Vt + (size_t)MM * DD;      // total 40 MB
    unsigned short* Ob  = xb;                        // alias: xb dead after qkv_gemm

    prep<<<8192, 256, 0, stream>>>(x, xb, Wq, Wk, Wv, Wo, Wt);

    qkv_gemm<<<dim3(DD / 128, MM / 128, 3), 256, 0, stream>>>(xb, Wt, bq, bk, bv, Qb, Kb, Vt);

    attn<<<dim3(16, 32), 512, 0, stream>>>(Qb, Kb, Vt, Ob);

    out_gemm<<<dim3(DD / 128, MM / 64), 256, 0, stream>>>(Ob, Wto, bo, out);
}

// Round 4
// 196.833 us; speedup vs baseline: 1.1024x; 1.0024x over previous
//
#include <hip/hip_runtime.h>
#include <hip/hip_bf16.h>

#define DEV __device__ __forceinline__

typedef short bf16x8 __attribute__((ext_vector_type(8)));
typedef float f32x4 __attribute__((ext_vector_type(4)));
typedef unsigned int u32;
typedef unsigned int u32x4 __attribute__((ext_vector_type(4)));

constexpr int BB = 2, SS = 2048, DD = 1024, HH = 16, DHD = 64;
constexpr int MM = BB * SS; // 4096
#define QSC 0.1803368801111f  /* 0.125 * log2(e): scores in log2 domain */

#if __has_builtin(__builtin_amdgcn_exp2f)
#define EXP2(x) __builtin_amdgcn_exp2f(x)
#else
#define EXP2(x) exp2f(x)
#endif

// round-half-up bf16; bias only at exact-half cases
DEV unsigned short f2bf(float f) {
    union { float f; unsigned int u; } v; v.f = f;
    return (unsigned short)((v.u + 0x8000u) >> 16);
}
// pack two f32 -> (bf16(b)<<16)|bf16(a) : add, add, v_perm = 3 instr
#if __has_builtin(__builtin_amdgcn_perm)
DEV u32 pk2bf(float a, float b) {
    union { float f; u32 u; } ua, ub; ua.f = a; ub.f = b;
    return __builtin_amdgcn_perm(ub.u + 0x8000u, ua.u + 0x8000u, 0x07060302u);
}
#else
DEV u32 pk2bf(float a, float b) {
    union { float f; u32 u; } ua, ub; ua.f = a; ub.f = b;
    return ((ua.u + 0x8000u) >> 16) | ((ub.u + 0x8000u) & 0xffff0000u);
}
#endif

// single-instruction RNE pack (gfx950 has no builtin; inline asm per T12)
DEV u32 cvtpk2bf(float a, float b) {
    u32 r;
    asm("v_cvt_pk_bf16_f32 %0, %1, %2" : "=v"(r) : "v"(a), "v"(b));
    return r;
}

DEV bf16x8 ld_bf16x8(const unsigned short* p) { return *(const bf16x8*)p; }

// async global->LDS, 16B per lane; lds dest = wave-uniform base + lane*16
DEV void gl16(const unsigned short* g, unsigned short* l) {
    __builtin_amdgcn_global_load_lds(
        (const __attribute__((address_space(1))) u32*)g,
        (__attribute__((address_space(3))) u32*)l, 16, 0, 0);
}

// ---- prep (fused): blocks [0,4096) = x->bf16 ; [4096,8192) = W transposes ----
__global__ void prep(const float* __restrict__ x, unsigned short* __restrict__ xb,
                     const float* __restrict__ W0, const float* __restrict__ W1,
                     const float* __restrict__ W2, const float* __restrict__ W3,
                     unsigned short* __restrict__ WtBase) {
    __shared__ float tile[32][33];
    int blk = blockIdx.x;
    if (blk < 4096) {
        int i = blk * 256 + threadIdx.x;
        float4 v = ((const float4*)x)[i];
        uint2 o;
        o.x = pk2bf(v.x, v.y);
        o.y = pk2bf(v.z, v.w);
        ((uint2*)xb)[i] = o;
        return;
    }
    blk -= 4096;                 // 4 weights x 1024 tiles
    int wsel = blk >> 10;
    const float* W = (wsel == 0) ? W0 : (wsel == 1) ? W1 : (wsel == 2) ? W2 : W3;
    unsigned short* Wt = WtBase + (size_t)wsel * DD * DD;
    int t = blk & 1023;
    int n0 = (t & 31) * 32, k0 = (t >> 5) * 32;
    int tx = threadIdx.x & 31, ty = threadIdx.x >> 5; // 32 x 8
    #pragma unroll
    for (int i = 0; i < 4; ++i)
        tile[ty + 8 * i][tx] = W[(size_t)(k0 + ty + 8 * i) * DD + n0 + tx];
    __syncthreads();
    #pragma unroll
    for (int i = 0; i < 4; ++i)
        Wt[(size_t)(n0 + ty + 8 * i) * DD + k0 + tx] = f2bf(tile[tx][ty + 8 * i]);
}

// ====================== QKV GEMM v3 ======================
// R3 fixes (counter-driven):
//  (a) LDS slot swizzle (row&3) -> ((row>>1)&3): rows are 64B (BK=32), so bank
//      quartet = 4*(row&1) + slotXOR. With row&3, even rows hit only 2 of 8
//      quartets -> measured 4-way conflict (3.14M = 4 extra cyc per b128 read).
//      With (row>>1)&3 the 8-row period walks all 8 quartets -> 2-way (free).
//  (b) XCD-balanced block remap: old mapping (xcd = blockIdx.x%8) made each XCD
//      stream ALL of xb (8MB) -> FETCH 68.7MB. New: each XCD owns a 4x(n) by
//      8x(m) tile block (A 2MB + B 1MB/z, ~L2-resident) -> predicted ~40MB.
__global__ __launch_bounds__(256) void qkv_gemm(
    const unsigned short* __restrict__ xb,
    const unsigned short* __restrict__ WtBase,
    const float* __restrict__ bq, const float* __restrict__ bk, const float* __restrict__ bv,
    unsigned short* __restrict__ Qb, unsigned short* __restrict__ Kb, unsigned short* __restrict__ Vt)
{
    __shared__ __align__(16) unsigned short Ald[2][128 * 32];
    __shared__ __align__(16) unsigned short Bld[2][128 * 32];

    const int z = blockIdx.z;
    const unsigned short* Wt = WtBase + (size_t)z * DD * DD;
    const float* bias = (z == 0) ? bq : (z == 1) ? bk : bv;

    // XCD-balanced remap: xcd k <- xe in [4(k&1),+4), ye in [8(k>>1),+8)
    const int gid2 = blockIdx.x + 8 * blockIdx.y;   // 0..255 per z; xcd = gid2&7
    const int xk = gid2 & 7, o = gid2 >> 3;
    const int xe = (xk & 1) * 4 + (o & 3);
    const int ye = (xk >> 1) * 8 + (o >> 2);
    const int m0g = ye * 128;
    const int n0g = xe * 128;

    const int wave = threadIdx.x >> 6, lane = threadIdx.x & 63;
    const int quad = lane >> 4, lcol = lane & 15;
    const int mb = (wave & 1) * 64, nb = (wave >> 1) * 64;

    f32x4 acc[4][4];
    #pragma unroll
    for (int i = 0; i < 4; ++i)
        #pragma unroll
        for (int j = 0; j < 4; ++j) acc[i][j] = (f32x4){0.f, 0.f, 0.f, 0.f};

    auto stage = [&](int ks, int bf) {
        #pragma unroll
        for (int i = 0; i < 4; ++i) {
            int j = wave * 4 + i;
            if (j < 8) { // A: xb rows m0g..m0g+127
                int bi = j * 64 + lane;
                int row = bi >> 2, p = (bi & 3) ^ ((row >> 1) & 3);
                gl16(xb + (size_t)(m0g + row) * DD + ks + p * 8, &Ald[bf][j * 512]);
            } else {     // B: Wt rows n0g..n0g+127
                int jj = j - 8;
                int bi = jj * 64 + lane;
                int row = bi >> 2, p = (bi & 3) ^ ((row >> 1) & 3);
                gl16(Wt + (size_t)(n0g + row) * DD + ks + p * 8, &Bld[bf][jj * 512]);
            }
        }
    };

    stage(0, 0);
    __syncthreads();

    for (int kk = 0; kk < 32; ++kk) {
        int bf = kk & 1;
        if (kk + 1 < 32) stage((kk + 1) * 32, (kk + 1) & 1);
        bf16x8 af[4], bfr[4];
        #pragma unroll
        for (int mt = 0; mt < 4; ++mt) {
            int row = mb + mt * 16 + lcol;
            af[mt] = ld_bf16x8(&Ald[bf][(row * 4 + (quad ^ ((row >> 1) & 3))) * 8]);
        }
        #pragma unroll
        for (int nt = 0; nt < 4; ++nt) {
            int row = nb + nt * 16 + lcol;
            bfr[nt] = ld_bf16x8(&Bld[bf][(row * 4 + (quad ^ ((row >> 1) & 3))) * 8]);
        }
        if (z < 2) { // transposed product: D[m=out_n][n=s]
            #pragma unroll
            for (int mt = 0; mt < 4; ++mt)
                #pragma unroll
                for (int nt = 0; nt < 4; ++nt)
                    acc[mt][nt] = __builtin_amdgcn_mfma_f32_16x16x32_bf16(bfr[nt], af[mt], acc[mt][nt], 0, 0, 0);
        } else {
            #pragma unroll
            for (int mt = 0; mt < 4; ++mt)
                #pragma unroll
                for (int nt = 0; nt < 4; ++nt)
                    acc[mt][nt] = __builtin_amdgcn_mfma_f32_16x16x32_bf16(af[mt], bfr[nt], acc[mt][nt], 0, 0, 0);
        }
        __syncthreads();
    }

    if (z < 2) {
        unsigned short* dst = (z == 0) ? Qb : Kb;
        const float sc = (z == 0) ? QSC : 1.0f;
        #pragma unroll
        for (int mt = 0; mt < 4; ++mt)
            #pragma unroll
            for (int nt = 0; nt < 4; ++nt) {
                int m = m0g + mb + mt * 16 + lcol;        // global row -> (b,s)
                int nbt = n0g + nb + nt * 16 + quad * 4;  // 4 consecutive out_n
                int b = m >> 11, s = m & (SS - 1);
                int h = nbt >> 6, dh0 = nbt & 63;
                float4 bv4 = *(const float4*)&bias[nbt];
                uint2 o2;
                o2.x = pk2bf((acc[mt][nt][0] + bv4.x) * sc, (acc[mt][nt][1] + bv4.y) * sc);
                o2.y = pk2bf((acc[mt][nt][2] + bv4.z) * sc, (acc[mt][nt][3] + bv4.w) * sc);
                *(uint2*)&dst[(((size_t)b * HH + h) * SS + s) * DHD + dh0] = o2;
            }
    } else {
        #pragma unroll
        for (int mt = 0; mt < 4; ++mt)
            #pragma unroll
            for (int nt = 0; nt < 4; ++nt) {
                int n = n0g + nb + nt * 16 + lcol;        // out_n
                int mbt = m0g + mb + mt * 16 + quad * 4;  // 4 consecutive global rows
                int h = n >> 6, dh = n & 63;
                int b = mbt >> 11, s0 = mbt & (SS - 1);
                float bvv = bias[n];
                uint2 o2;
                o2.x = pk2bf(acc[mt][nt][0] + bvv, acc[mt][nt][1] + bvv);
                o2.y = pk2bf(acc[mt][nt][2] + bvv, acc[mt][nt][3] + bvv);
                *(uint2*)&Vt[(((size_t)b * HH + h) * DHD + dh) * SS + s0] = o2;
            }
    }
}

// ====================== attention v10: v7 + P-in-register (tb eliminated) ======================
// Identical to v7 (58.5us, 0 conflicts) except: QK loads K-rows in the permuted
// order kr = kf2*32 + 8*(lcol>>2) + 4*j + (lcol&3), so the S-output regs of MFMA
// pair j=0,1 concatenate into the PV A-fragment (keys 8*quad..8*quad+7) directly
// in registers (2x v_cvt_pk_bf16_f32 each). tb LDS round-trip deleted.
__global__ __launch_bounds__(512, 4) void attn(
    const unsigned short* __restrict__ Qb,
    const unsigned short* __restrict__ Kb,
    const unsigned short* __restrict__ Vt,
    unsigned short* __restrict__ Ob)
{
    __shared__ __align__(16) unsigned short Kld[2][64 * 64]; // keys x dh, swz(r)-swizzled blocks
    __shared__ __align__(16) unsigned short Vld[2][64 * 64]; // dh x keys, (dh&7)-swizzled blocks

    const int g = blockIdx.y * gridDim.x + blockIdx.x;  // grid (16, 32) = 512
    const int bh = (g & 7) * 4 + ((g >> 3) & 3);        // fixed g%32 per bh -> fixed XCD
    const int qt = g >> 5;                               // 0..15
    const int b = bh >> 4, h = bh & (HH - 1);
    const unsigned short* Qbh = Qb + (size_t)bh * SS * DHD;
    const unsigned short* Kbh = Kb + (size_t)bh * SS * DHD;
    const unsigned short* Vbh = Vt + (size_t)bh * DHD * SS;

    const int wave = threadIdx.x >> 6, lane = threadIdx.x & 63;
    const int quad = lane >> 4, lcol = lane & 15;
    const int rowbase = qt * 128 + wave * 16;

    // Q B-frags (n = q-row, k = dh); 0.125*log2e folded into Q
    bf16x8 qf0 = ld_bf16x8(Qbh + (size_t)(rowbase + lcol) * DHD + quad * 8);
    bf16x8 qf1 = ld_bf16x8(Qbh + (size_t)(rowbase + lcol) * DHD + 32 + quad * 8);

    // K-row this lane reads for QK MFMA-pair (kf2, j): keys 8q+4j+r land in regs
    auto krow = [&](int kf2, int j) {
        return kf2 * 32 + ((lcol >> 2) << 3) + j * 4 + (lcol & 3);
    };
    auto kswz = [](int r) { return (r & 3) | (((r >> 3) & 1) << 2); };

    auto stage = [&](int c, int bf) {
        int kb = c * 64;
        #pragma unroll
        for (int i = 0; i < 2; ++i) {
            int j = wave * 2 + i;
            if (j < 8) { // K: rows = keys, 8 parts of dh, swz(r) slot permutation
                int bi = j * 64 + lane;
                int r = bi >> 3, p = (bi & 7) ^ ((r & 3) | (((r >> 3) & 1) << 2));
                gl16(Kbh + (size_t)(kb + r) * DHD + p * 8, &Kld[bf][j * 512]);
            } else {     // V: rows = dh, 8 parts of keys
                int jj = j - 8;
                int bi = jj * 64 + lane;
                int dh = bi >> 3, p = (bi & 7) ^ (dh & 7);
                gl16(Vbh + (size_t)dh * SS + kb + p * 8, &Vld[bf][jj * 512]);
            }
        }
    };

    // ---- prologue: stage chunk 0, wave-uniform m0 estimate from it ----
    stage(0, 0);
    __syncthreads();

    float m0 = -1e30f;
    #pragma unroll
    for (int kf2 = 0; kf2 < 2; ++kf2)
        #pragma unroll
        for (int j = 0; j < 2; ++j) {
            int kr = krow(kf2, j), sw = kswz(kr);
            bf16x8 ka0 = ld_bf16x8(&Kld[0][(kr * 8 + (quad ^ sw)) * 8]);
            bf16x8 ka1 = ld_bf16x8(&Kld[0][(kr * 8 + ((quad + 4) ^ sw)) * 8]);
            f32x4 s = (f32x4){0.f, 0.f, 0.f, 0.f};
            s = __builtin_amdgcn_mfma_f32_16x16x32_bf16(ka0, qf0, s, 0, 0, 0);
            s = __builtin_amdgcn_mfma_f32_16x16x32_bf16(ka1, qf1, s, 0, 0, 0);
            #pragma unroll
            for (int r = 0; r < 4; ++r) m0 = fmaxf(m0, s[r]);
        }
    #pragma unroll
    for (int msk = 1; msk < 64; msk <<= 1) m0 = fmaxf(m0, __shfl_xor(m0, msk, 64));
    const f32x4 minit = (f32x4){-m0, -m0, -m0, -m0};

    // ---- main loop over 32 chunks of 64 keys ----
    f32x4 oacc[4];
    #pragma unroll
    for (int nt = 0; nt < 4; ++nt) oacc[nt] = (f32x4){0.f, 0.f, 0.f, 0.f};
    float ps = 0.f;

    for (int c = 0; c < 32; ++c) {
        int bf = c & 1;
        if (c + 1 < 32) stage(c + 1, (c + 1) & 1);

        // S^T = K.Q^T (C-init = -m0) -> exp2 -> pack into PV A-frags (registers)
        bf16x8 paf[2];
        #pragma unroll
        for (int kf2 = 0; kf2 < 2; ++kf2) {
            u32 w[4];
            #pragma unroll
            for (int j = 0; j < 2; ++j) {
                int kr = krow(kf2, j), sw = kswz(kr);
                bf16x8 ka0 = ld_bf16x8(&Kld[bf][(kr * 8 + (quad ^ sw)) * 8]);
                bf16x8 ka1 = ld_bf16x8(&Kld[bf][(kr * 8 + ((quad + 4) ^ sw)) * 8]);
                f32x4 s = minit;
                s = __builtin_amdgcn_mfma_f32_16x16x32_bf16(ka0, qf0, s, 0, 0, 0);
                s = __builtin_amdgcn_mfma_f32_16x16x32_bf16(ka1, qf1, s, 0, 0, 0);
                float e0 = EXP2(s[0]), e1 = EXP2(s[1]);
                float e2 = EXP2(s[2]), e3 = EXP2(s[3]);
                ps += (e0 + e1) + (e2 + e3);
                w[j * 2]     = cvtpk2bf(e0, e1);
                w[j * 2 + 1] = cvtpk2bf(e2, e3);
            }
            union { u32x4 u; bf16x8 v; } pu;
            pu.u = (u32x4){w[0], w[1], w[2], w[3]};
            paf[kf2] = pu.v;
        }

        // PV: A = P (registers), B = V (from Vld) — identical to v7 reads
        #pragma unroll
        for (int kf2 = 0; kf2 < 2; ++kf2) {
            #pragma unroll
            for (int nt = 0; nt < 4; ++nt) {
                int dh = nt * 16 + lcol;
                bf16x8 vb = ld_bf16x8(&Vld[bf][(dh * 8 + ((kf2 * 4 + quad) ^ (dh & 7))) * 8]);
                oacc[nt] = __builtin_amdgcn_mfma_f32_16x16x32_bf16(paf[kf2], vb, oacc[nt], 0, 0, 0);
            }
        }
        __syncthreads();
    }

    // ---- epilogue: per-row normalize (rows owned entirely by this wave) ----
    ps += __shfl_xor(ps, 16, 64);
    ps += __shfl_xor(ps, 32, 64);
    float inv = 1.0f / ps;   // valid at lanes where lcol == q-row
    #pragma unroll
    for (int r = 0; r < 4; ++r) {
        float iv = __shfl(inv, quad * 4 + r, 64);
        int srow = rowbase + quad * 4 + r;
        size_t base = (((size_t)b * SS + srow) * HH + h) * DHD;
        #pragma unroll
        for (int nt = 0; nt < 4; ++nt)
            Ob[base + nt * 16 + lcol] = f2bf(oacc[nt][r] * iv);
    }
}

// ====================== output GEMM v2 ======================
// Tile 64 tokens x 128 out_n, BK=64 dbuf (16 barriers), transposed product:
// A = Wto (rows = out_n), B = Ob (rows = tokens) -> D[m=out_n][n=token];
// reg-quad r gives 4 consecutive out_n -> float4 stores (8 per thread).
// LDS frag swizzle = attn Kld 8-part scheme (measured 0 conflicts).
__global__ __launch_bounds__(256) void out_gemm(
    const unsigned short* __restrict__ Ob,
    const unsigned short* __restrict__ Wto,
    const float* __restrict__ bo,
    float* __restrict__ out)
{
    __shared__ __align__(16) unsigned short Wld[2][128 * 64]; // out_n x k
    __shared__ __align__(16) unsigned short Old[2][64 * 64];  // token x k

    const int m0g = blockIdx.y * 64;    // tokens
    const int n0g = blockIdx.x * 128;   // out_n
    const int wave = threadIdx.x >> 6, lane = threadIdx.x & 63;
    const int quad = lane >> 4, lcol = lane & 15;
    const int nb = wave * 32;           // wave's out_n sub-range

    f32x4 acc[2][4];
    #pragma unroll
    for (int i = 0; i < 2; ++i)
        #pragma unroll
        for (int j = 0; j < 4; ++j) acc[i][j] = (f32x4){0.f, 0.f, 0.f, 0.f};

    auto stage = [&](int ks, int bf) {
        #pragma unroll
        for (int i = 0; i < 6; ++i) {
            int j = wave * 6 + i;
            if (j < 16) { // W: 128 rows x 8 parts
                int bi = j * 64 + lane;
                int r = bi >> 3, p = (bi & 7) ^ (r & 7);
                gl16(Wto + (size_t)(n0g + r) * DD + ks + p * 8, &Wld[bf][j * 512]);
            } else {      // Ob: 64 rows x 8 parts
                int jj = j - 16;
                int bi = jj * 64 + lane;
                int r = bi >> 3, p = (bi & 7) ^ (r & 7);
                gl16(Ob + (size_t)(m0g + r) * DD + ks + p * 8, &Old[bf][jj * 512]);
            }
        }
    };

    stage(0, 0);
    __syncthreads();

    for (int kk = 0; kk < 16; ++kk) {
        int bf = kk & 1;
        if (kk + 1 < 16) stage((kk + 1) * 64, (kk + 1) & 1);
        #pragma unroll
        for (int kh = 0; kh < 2; ++kh) {
            bf16x8 wf[2], of[4];
            #pragma unroll
            for (int i = 0; i < 2; ++i) {
                int row = nb + i * 16 + lcol;
                wf[i] = ld_bf16x8(&Wld[bf][(row * 8 + ((kh * 4 + quad) ^ (row & 7))) * 8]);
            }
            #pragma unroll
            for (int j = 0; j < 4; ++j) {
                int row = j * 16 + lcol;
                of[j] = ld_bf16x8(&Old[bf][(row * 8 + ((kh * 4 + quad) ^ (row & 7))) * 8]);
            }
            #pragma unroll
            for (int i = 0; i < 2; ++i)
                #pragma unroll
                for (int j = 0; j < 4; ++j)
                    acc[i][j] = __builtin_amdgcn_mfma_f32_16x16x32_bf16(wf[i], of[j], acc[i][j], 0, 0, 0);
        }
        __syncthreads();
    }

    // C: col = token (lcol within j-tile), row = out_n (quad*4 + r, consecutive)
    #pragma unroll
    for (int i = 0; i < 2; ++i) {
        int n4 = n0g + nb + i * 16 + quad * 4;
        float4 bv4 = *(const float4*)&bo[n4];
        #pragma unroll
        for (int j = 0; j < 4; ++j) {
            int token = m0g + j * 16 + lcol;
            float4 o;
            o.x = acc[i][j][0] + bv4.x;
            o.y = acc[i][j][1] + bv4.y;
            o.z = acc[i][j][2] + bv4.z;
            o.w = acc[i][j][3] + bv4.w;
            *(float4*)&out[(size_t)token * DD + n4] = o;
        }
    }
}

extern "C" void kernel_launch(void* const* d_in, const int* in_sizes, int n_in,
                              void* d_out, int out_size, void* d_ws, size_t ws_size,
                              hipStream_t stream)
{
    const float* x  = (const float*)d_in[0];
    const float* Wq = (const float*)d_in[1];
    const float* bq = (const float*)d_in[2];
    const float* Wk = (const float*)d_in[3];
    const float* bk = (const float*)d_in[4];
    const float* Wv = (const float*)d_in[5];
    const float* bv = (const float*)d_in[6];
    const float* Wo = (const float*)d_in[7];
    const float* bo = (const float*)d_in[8];
    float* out = (float*)d_out;

    unsigned short* ws = (unsigned short*)d_ws;
    unsigned short* Wt  = ws;                        // 4 * D*D (q,k,v,o)
    unsigned short* Wto = Wt + 3 * (size_t)DD * DD;
    unsigned short* Qb  = Wt + 4 * (size_t)DD * DD;  // M*D each
    unsigned short* Kb  = Qb + (size_t)MM * DD;
    unsigned short* Vt  = Kb + (size_t)MM * DD;
    unsigned short* xb  = Vt + (size_t)MM * DD;      // total 40 MB
    unsigned short* Ob  = xb;                        // alias: xb dead after qkv_gemm

    prep<<<8192, 256, 0, stream>>>(x, xb, Wq, Wk, Wv, Wo, Wt);

    qkv_gemm<<<dim3(8, 32, 3), 256, 0, stream>>>(xb, Wt, bq, bk, bv, Qb, Kb, Vt);

    attn<<<dim3(16, 32), 512, 0, stream>>>(Qb, Kb, Vt, Ob);

    out_gemm<<<dim3(DD / 128, MM / 64), 256, 0, stream>>>(Ob, Wto, bo, out);
}

// Round 5
// 195.047 us; speedup vs baseline: 1.1125x; 1.0092x over previous
//
#include <hip/hip_runtime.h>
#include <hip/hip_bf16.h>

#define DEV __device__ __forceinline__

typedef short bf16x8 __attribute__((ext_vector_type(8)));
typedef float f32x4 __attribute__((ext_vector_type(4)));
typedef unsigned int u32;
typedef unsigned int u32x4 __attribute__((ext_vector_type(4)));

constexpr int BB = 2, SS = 2048, DD = 1024, HH = 16, DHD = 64;
constexpr int MM = BB * SS; // 4096
#define QSC 0.1803368801111f  /* 0.125 * log2(e): scores in log2 domain */

#if __has_builtin(__builtin_amdgcn_exp2f)
#define EXP2(x) __builtin_amdgcn_exp2f(x)
#else
#define EXP2(x) exp2f(x)
#endif

// round-half-up bf16; bias only at exact-half cases
DEV unsigned short f2bf(float f) {
    union { float f; unsigned int u; } v; v.f = f;
    return (unsigned short)((v.u + 0x8000u) >> 16);
}
// pack two f32 -> (bf16(b)<<16)|bf16(a) : add, add, v_perm = 3 instr
#if __has_builtin(__builtin_amdgcn_perm)
DEV u32 pk2bf(float a, float b) {
    union { float f; u32 u; } ua, ub; ua.f = a; ub.f = b;
    return __builtin_amdgcn_perm(ub.u + 0x8000u, ua.u + 0x8000u, 0x07060302u);
}
#else
DEV u32 pk2bf(float a, float b) {
    union { float f; u32 u; } ua, ub; ua.f = a; ub.f = b;
    return ((ua.u + 0x8000u) >> 16) | ((ub.u + 0x8000u) & 0xffff0000u);
}
#endif

// single-instruction RNE pack (gfx950 has no builtin; inline asm per T12)
DEV u32 cvtpk2bf(float a, float b) {
    u32 r;
    asm("v_cvt_pk_bf16_f32 %0, %1, %2" : "=v"(r) : "v"(a), "v"(b));
    return r;
}

DEV bf16x8 ld_bf16x8(const unsigned short* p) { return *(const bf16x8*)p; }

// async global->LDS, 16B per lane; lds dest = wave-uniform base + lane*16
DEV void gl16(const unsigned short* g, unsigned short* l) {
    __builtin_amdgcn_global_load_lds(
        (const __attribute__((address_space(1))) u32*)g,
        (__attribute__((address_space(3))) u32*)l, 16, 0, 0);
}

// ---- prep (fused): blocks [0,4096) = x->bf16 ; [4096,8192) = W transposes ----
__global__ void prep(const float* __restrict__ x, unsigned short* __restrict__ xb,
                     const float* __restrict__ W0, const float* __restrict__ W1,
                     const float* __restrict__ W2, const float* __restrict__ W3,
                     unsigned short* __restrict__ WtBase) {
    __shared__ float tile[32][33];
    int blk = blockIdx.x;
    if (blk < 4096) {
        int i = blk * 256 + threadIdx.x;
        float4 v = ((const float4*)x)[i];
        uint2 o;
        o.x = pk2bf(v.x, v.y);
        o.y = pk2bf(v.z, v.w);
        ((uint2*)xb)[i] = o;
        return;
    }
    blk -= 4096;                 // 4 weights x 1024 tiles
    int wsel = blk >> 10;
    const float* W = (wsel == 0) ? W0 : (wsel == 1) ? W1 : (wsel == 2) ? W2 : W3;
    unsigned short* Wt = WtBase + (size_t)wsel * DD * DD;
    int t = blk & 1023;
    int n0 = (t & 31) * 32, k0 = (t >> 5) * 32;
    int tx = threadIdx.x & 31, ty = threadIdx.x >> 5; // 32 x 8
    #pragma unroll
    for (int i = 0; i < 4; ++i)
        tile[ty + 8 * i][tx] = W[(size_t)(k0 + ty + 8 * i) * DD + n0 + tx];
    __syncthreads();
    #pragma unroll
    for (int i = 0; i < 4; ++i)
        Wt[(size_t)(n0 + ty + 8 * i) * DD + k0 + tx] = f2bf(tile[tx][ty + 8 * i]);
}

// ====================== QKV GEMM v4: 3-buffer, counted vmcnt (T3+T4) ======================
// R4 change: the v3 structure was barrier-latency-bound (MfmaUtil 18.5%, VALU 42%,
// HBM 13%, conflicts 0 -> nothing saturated; wall ~3860 cyc per K-step-slot vs
// ~930 MFMA + ~860 DS). Cause: __syncthreads() emits s_waitcnt vmcnt(0), draining
// the just-issued stage(k+1) DMA every K-step. Fix: 3 LDS buffers, stage(k+2)
// 2-deep prefetch, raw s_barrier + counted "s_waitcnt vmcnt(8)" (4 gl16 per wave
// per stage -> 8 = stages k+1,k+2 in flight, stage(k) retired). Never drains to 0
// in the main loop; tail peeled with vmcnt(4)/vmcnt(0).
__global__ __launch_bounds__(256) void qkv_gemm(
    const unsigned short* __restrict__ xb,
    const unsigned short* __restrict__ WtBase,
    const float* __restrict__ bq, const float* __restrict__ bk, const float* __restrict__ bv,
    unsigned short* __restrict__ Qb, unsigned short* __restrict__ Kb, unsigned short* __restrict__ Vt)
{
    __shared__ __align__(16) unsigned short Ald[3][128 * 32];
    __shared__ __align__(16) unsigned short Bld[3][128 * 32];

    const int z = blockIdx.z;
    const unsigned short* Wt = WtBase + (size_t)z * DD * DD;
    const float* bias = (z == 0) ? bq : (z == 1) ? bk : bv;

    // XCD-balanced remap: xcd k <- xe in [4(k&1),+4), ye in [8(k>>1),+8)
    const int gid2 = blockIdx.x + 8 * blockIdx.y;   // 0..255 per z; xcd = gid2&7
    const int xk = gid2 & 7, o = gid2 >> 3;
    const int xe = (xk & 1) * 4 + (o & 3);
    const int ye = (xk >> 1) * 8 + (o >> 2);
    const int m0g = ye * 128;
    const int n0g = xe * 128;

    const int wave = threadIdx.x >> 6, lane = threadIdx.x & 63;
    const int quad = lane >> 4, lcol = lane & 15;
    const int mb = (wave & 1) * 64, nb = (wave >> 1) * 64;

    f32x4 acc[4][4];
    #pragma unroll
    for (int i = 0; i < 4; ++i)
        #pragma unroll
        for (int j = 0; j < 4; ++j) acc[i][j] = (f32x4){0.f, 0.f, 0.f, 0.f};

    // 4 gl16 per wave per stage (vmcnt unit)
    auto stage = [&](int ks, int bf) {
        #pragma unroll
        for (int i = 0; i < 4; ++i) {
            int j = wave * 4 + i;
            if (j < 8) { // A: xb rows m0g..m0g+127
                int bi = j * 64 + lane;
                int row = bi >> 2, p = (bi & 3) ^ ((row >> 1) & 3);
                gl16(xb + (size_t)(m0g + row) * DD + ks + p * 8, &Ald[bf][j * 512]);
            } else {     // B: Wt rows n0g..n0g+127
                int jj = j - 8;
                int bi = jj * 64 + lane;
                int row = bi >> 2, p = (bi & 3) ^ ((row >> 1) & 3);
                gl16(Wt + (size_t)(n0g + row) * DD + ks + p * 8, &Bld[bf][jj * 512]);
            }
        }
    };

    auto compute = [&](int bf) {
        bf16x8 af[4], bfr[4];
        #pragma unroll
        for (int mt = 0; mt < 4; ++mt) {
            int row = mb + mt * 16 + lcol;
            af[mt] = ld_bf16x8(&Ald[bf][(row * 4 + (quad ^ ((row >> 1) & 3))) * 8]);
        }
        #pragma unroll
        for (int nt = 0; nt < 4; ++nt) {
            int row = nb + nt * 16 + lcol;
            bfr[nt] = ld_bf16x8(&Bld[bf][(row * 4 + (quad ^ ((row >> 1) & 3))) * 8]);
        }
        if (z < 2) { // transposed product: D[m=out_n][n=s]
            #pragma unroll
            for (int mt = 0; mt < 4; ++mt)
                #pragma unroll
                for (int nt = 0; nt < 4; ++nt)
                    acc[mt][nt] = __builtin_amdgcn_mfma_f32_16x16x32_bf16(bfr[nt], af[mt], acc[mt][nt], 0, 0, 0);
        } else {
            #pragma unroll
            for (int mt = 0; mt < 4; ++mt)
                #pragma unroll
                for (int nt = 0; nt < 4; ++nt)
                    acc[mt][nt] = __builtin_amdgcn_mfma_f32_16x16x32_bf16(af[mt], bfr[nt], acc[mt][nt], 0, 0, 0);
        }
    };

    stage(0, 0);
    stage(32, 1);

    // main loop: k = 0..29, buffers (k%3); vmcnt(8) = 2 stages in flight
    for (int kk = 0; kk < 30; kk += 3) {
        #pragma unroll
        for (int u = 0; u < 3; ++u) {
            int k = kk + u;
            stage((k + 2) * 32, (u + 2) % 3);
            asm volatile("s_waitcnt vmcnt(8)" ::: "memory");
            __builtin_amdgcn_s_barrier();
            __builtin_amdgcn_sched_barrier(0);
            compute(u);
            __builtin_amdgcn_s_barrier();
        }
    }
    // k = 30 (buf 0): only stage(31) in flight
    asm volatile("s_waitcnt vmcnt(4)" ::: "memory");
    __builtin_amdgcn_s_barrier();
    __builtin_amdgcn_sched_barrier(0);
    compute(0);
    __builtin_amdgcn_s_barrier();
    // k = 31 (buf 1): drain
    asm volatile("s_waitcnt vmcnt(0)" ::: "memory");
    __builtin_amdgcn_s_barrier();
    __builtin_amdgcn_sched_barrier(0);
    compute(1);

    if (z < 2) {
        unsigned short* dst = (z == 0) ? Qb : Kb;
        const float sc = (z == 0) ? QSC : 1.0f;
        #pragma unroll
        for (int mt = 0; mt < 4; ++mt)
            #pragma unroll
            for (int nt = 0; nt < 4; ++nt) {
                int m = m0g + mb + mt * 16 + lcol;        // global row -> (b,s)
                int nbt = n0g + nb + nt * 16 + quad * 4;  // 4 consecutive out_n
                int b = m >> 11, s = m & (SS - 1);
                int h = nbt >> 6, dh0 = nbt & 63;
                float4 bv4 = *(const float4*)&bias[nbt];
                uint2 o2;
                o2.x = pk2bf((acc[mt][nt][0] + bv4.x) * sc, (acc[mt][nt][1] + bv4.y) * sc);
                o2.y = pk2bf((acc[mt][nt][2] + bv4.z) * sc, (acc[mt][nt][3] + bv4.w) * sc);
                *(uint2*)&dst[(((size_t)b * HH + h) * SS + s) * DHD + dh0] = o2;
            }
    } else {
        #pragma unroll
        for (int mt = 0; mt < 4; ++mt)
            #pragma unroll
            for (int nt = 0; nt < 4; ++nt) {
                int n = n0g + nb + nt * 16 + lcol;        // out_n
                int mbt = m0g + mb + mt * 16 + quad * 4;  // 4 consecutive global rows
                int h = n >> 6, dh = n & 63;
                int b = mbt >> 11, s0 = mbt & (SS - 1);
                float bvv = bias[n];
                uint2 o2;
                o2.x = pk2bf(acc[mt][nt][0] + bvv, acc[mt][nt][1] + bvv);
                o2.y = pk2bf(acc[mt][nt][2] + bvv, acc[mt][nt][3] + bvv);
                *(uint2*)&Vt[(((size_t)b * HH + h) * DHD + dh) * SS + s0] = o2;
            }
    }
}

// ====================== attention v10: v7 + P-in-register (tb eliminated) ======================
// Identical to v7 (58.5us, 0 conflicts) except: QK loads K-rows in the permuted
// order kr = kf2*32 + 8*(lcol>>2) + 4*j + (lcol&3), so the S-output regs of MFMA
// pair j=0,1 concatenate into the PV A-fragment (keys 8*quad..8*quad+7) directly
// in registers (2x v_cvt_pk_bf16_f32 each). tb LDS round-trip deleted.
__global__ __launch_bounds__(512, 4) void attn(
    const unsigned short* __restrict__ Qb,
    const unsigned short* __restrict__ Kb,
    const unsigned short* __restrict__ Vt,
    unsigned short* __restrict__ Ob)
{
    __shared__ __align__(16) unsigned short Kld[2][64 * 64]; // keys x dh, swz(r)-swizzled blocks
    __shared__ __align__(16) unsigned short Vld[2][64 * 64]; // dh x keys, (dh&7)-swizzled blocks

    const int g = blockIdx.y * gridDim.x + blockIdx.x;  // grid (16, 32) = 512
    const int bh = (g & 7) * 4 + ((g >> 3) & 3);        // fixed g%32 per bh -> fixed XCD
    const int qt = g >> 5;                               // 0..15
    const int b = bh >> 4, h = bh & (HH - 1);
    const unsigned short* Qbh = Qb + (size_t)bh * SS * DHD;
    const unsigned short* Kbh = Kb + (size_t)bh * SS * DHD;
    const unsigned short* Vbh = Vt + (size_t)bh * DHD * SS;

    const int wave = threadIdx.x >> 6, lane = threadIdx.x & 63;
    const int quad = lane >> 4, lcol = lane & 15;
    const int rowbase = qt * 128 + wave * 16;

    // Q B-frags (n = q-row, k = dh); 0.125*log2e folded into Q
    bf16x8 qf0 = ld_bf16x8(Qbh + (size_t)(rowbase + lcol) * DHD + quad * 8);
    bf16x8 qf1 = ld_bf16x8(Qbh + (size_t)(rowbase + lcol) * DHD + 32 + quad * 8);

    // K-row this lane reads for QK MFMA-pair (kf2, j): keys 8q+4j+r land in regs
    auto krow = [&](int kf2, int j) {
        return kf2 * 32 + ((lcol >> 2) << 3) + j * 4 + (lcol & 3);
    };
    auto kswz = [](int r) { return (r & 3) | (((r >> 3) & 1) << 2); };

    auto stage = [&](int c, int bf) {
        int kb = c * 64;
        #pragma unroll
        for (int i = 0; i < 2; ++i) {
            int j = wave * 2 + i;
            if (j < 8) { // K: rows = keys, 8 parts of dh, swz(r) slot permutation
                int bi = j * 64 + lane;
                int r = bi >> 3, p = (bi & 7) ^ ((r & 3) | (((r >> 3) & 1) << 2));
                gl16(Kbh + (size_t)(kb + r) * DHD + p * 8, &Kld[bf][j * 512]);
            } else {     // V: rows = dh, 8 parts of keys
                int jj = j - 8;
                int bi = jj * 64 + lane;
                int dh = bi >> 3, p = (bi & 7) ^ (dh & 7);
                gl16(Vbh + (size_t)dh * SS + kb + p * 8, &Vld[bf][jj * 512]);
            }
        }
    };

    // ---- prologue: stage chunk 0, wave-uniform m0 estimate from it ----
    stage(0, 0);
    __syncthreads();

    float m0 = -1e30f;
    #pragma unroll
    for (int kf2 = 0; kf2 < 2; ++kf2)
        #pragma unroll
        for (int j = 0; j < 2; ++j) {
            int kr = krow(kf2, j), sw = kswz(kr);
            bf16x8 ka0 = ld_bf16x8(&Kld[0][(kr * 8 + (quad ^ sw)) * 8]);
            bf16x8 ka1 = ld_bf16x8(&Kld[0][(kr * 8 + ((quad + 4) ^ sw)) * 8]);
            f32x4 s = (f32x4){0.f, 0.f, 0.f, 0.f};
            s = __builtin_amdgcn_mfma_f32_16x16x32_bf16(ka0, qf0, s, 0, 0, 0);
            s = __builtin_amdgcn_mfma_f32_16x16x32_bf16(ka1, qf1, s, 0, 0, 0);
            #pragma unroll
            for (int r = 0; r < 4; ++r) m0 = fmaxf(m0, s[r]);
        }
    #pragma unroll
    for (int msk = 1; msk < 64; msk <<= 1) m0 = fmaxf(m0, __shfl_xor(m0, msk, 64));
    const f32x4 minit = (f32x4){-m0, -m0, -m0, -m0};

    // ---- main loop over 32 chunks of 64 keys ----
    f32x4 oacc[4];
    #pragma unroll
    for (int nt = 0; nt < 4; ++nt) oacc[nt] = (f32x4){0.f, 0.f, 0.f, 0.f};
    float ps = 0.f;

    for (int c = 0; c < 32; ++c) {
        int bf = c & 1;
        if (c + 1 < 32) stage(c + 1, (c + 1) & 1);

        // S^T = K.Q^T (C-init = -m0) -> exp2 -> pack into PV A-frags (registers)
        bf16x8 paf[2];
        #pragma unroll
        for (int kf2 = 0; kf2 < 2; ++kf2) {
            u32 w[4];
            #pragma unroll
            for (int j = 0; j < 2; ++j) {
                int kr = krow(kf2, j), sw = kswz(kr);
                bf16x8 ka0 = ld_bf16x8(&Kld[bf][(kr * 8 + (quad ^ sw)) * 8]);
                bf16x8 ka1 = ld_bf16x8(&Kld[bf][(kr * 8 + ((quad + 4) ^ sw)) * 8]);
                f32x4 s = minit;
                s = __builtin_amdgcn_mfma_f32_16x16x32_bf16(ka0, qf0, s, 0, 0, 0);
                s = __builtin_amdgcn_mfma_f32_16x16x32_bf16(ka1, qf1, s, 0, 0, 0);
                float e0 = EXP2(s[0]), e1 = EXP2(s[1]);
                float e2 = EXP2(s[2]), e3 = EXP2(s[3]);
                ps += (e0 + e1) + (e2 + e3);
                w[j * 2]     = cvtpk2bf(e0, e1);
                w[j * 2 + 1] = cvtpk2bf(e2, e3);
            }
            union { u32x4 u; bf16x8 v; } pu;
            pu.u = (u32x4){w[0], w[1], w[2], w[3]};
            paf[kf2] = pu.v;
        }

        // PV: A = P (registers), B = V (from Vld) — identical to v7 reads
        #pragma unroll
        for (int kf2 = 0; kf2 < 2; ++kf2) {
            #pragma unroll
            for (int nt = 0; nt < 4; ++nt) {
                int dh = nt * 16 + lcol;
                bf16x8 vb = ld_bf16x8(&Vld[bf][(dh * 8 + ((kf2 * 4 + quad) ^ (dh & 7))) * 8]);
                oacc[nt] = __builtin_amdgcn_mfma_f32_16x16x32_bf16(paf[kf2], vb, oacc[nt], 0, 0, 0);
            }
        }
        __syncthreads();
    }

    // ---- epilogue: per-row normalize (rows owned entirely by this wave) ----
    ps += __shfl_xor(ps, 16, 64);
    ps += __shfl_xor(ps, 32, 64);
    float inv = 1.0f / ps;   // valid at lanes where lcol == q-row
    #pragma unroll
    for (int r = 0; r < 4; ++r) {
        float iv = __shfl(inv, quad * 4 + r, 64);
        int srow = rowbase + quad * 4 + r;
        size_t base = (((size_t)b * SS + srow) * HH + h) * DHD;
        #pragma unroll
        for (int nt = 0; nt < 4; ++nt)
            Ob[base + nt * 16 + lcol] = f2bf(oacc[nt][r] * iv);
    }
}

// ====================== output GEMM v2 ======================
// Tile 64 tokens x 128 out_n, BK=64 dbuf (16 barriers), transposed product:
// A = Wto (rows = out_n), B = Ob (rows = tokens) -> D[m=out_n][n=token];
// reg-quad r gives 4 consecutive out_n -> float4 stores (8 per thread).
// LDS frag swizzle = attn Kld 8-part scheme (measured 0 conflicts).
__global__ __launch_bounds__(256) void out_gemm(
    const unsigned short* __restrict__ Ob,
    const unsigned short* __restrict__ Wto,
    const float* __restrict__ bo,
    float* __restrict__ out)
{
    __shared__ __align__(16) unsigned short Wld[2][128 * 64]; // out_n x k
    __shared__ __align__(16) unsigned short Old[2][64 * 64];  // token x k

    const int m0g = blockIdx.y * 64;    // tokens
    const int n0g = blockIdx.x * 128;   // out_n
    const int wave = threadIdx.x >> 6, lane = threadIdx.x & 63;
    const int quad = lane >> 4, lcol = lane & 15;
    const int nb = wave * 32;           // wave's out_n sub-range

    f32x4 acc[2][4];
    #pragma unroll
    for (int i = 0; i < 2; ++i)
        #pragma unroll
        for (int j = 0; j < 4; ++j) acc[i][j] = (f32x4){0.f, 0.f, 0.f, 0.f};

    auto stage = [&](int ks, int bf) {
        #pragma unroll
        for (int i = 0; i < 6; ++i) {
            int j = wave * 6 + i;
            if (j < 16) { // W: 128 rows x 8 parts
                int bi = j * 64 + lane;
                int r = bi >> 3, p = (bi & 7) ^ (r & 7);
                gl16(Wto + (size_t)(n0g + r) * DD + ks + p * 8, &Wld[bf][j * 512]);
            } else {      // Ob: 64 rows x 8 parts
                int jj = j - 16;
                int bi = jj * 64 + lane;
                int r = bi >> 3, p = (bi & 7) ^ (r & 7);
                gl16(Ob + (size_t)(m0g + r) * DD + ks + p * 8, &Old[bf][jj * 512]);
            }
        }
    };

    stage(0, 0);
    __syncthreads();

    for (int kk = 0; kk < 16; ++kk) {
        int bf = kk & 1;
        if (kk + 1 < 16) stage((kk + 1) * 64, (kk + 1) & 1);
        #pragma unroll
        for (int kh = 0; kh < 2; ++kh) {
            bf16x8 wf[2], of[4];
            #pragma unroll
            for (int i = 0; i < 2; ++i) {
                int row = nb + i * 16 + lcol;
                wf[i] = ld_bf16x8(&Wld[bf][(row * 8 + ((kh * 4 + quad) ^ (row & 7))) * 8]);
            }
            #pragma unroll
            for (int j = 0; j < 4; ++j) {
                int row = j * 16 + lcol;
                of[j] = ld_bf16x8(&Old[bf][(row * 8 + ((kh * 4 + quad) ^ (row & 7))) * 8]);
            }
            #pragma unroll
            for (int i = 0; i < 2; ++i)
                #pragma unroll
                for (int j = 0; j < 4; ++j)
                    acc[i][j] = __builtin_amdgcn_mfma_f32_16x16x32_bf16(wf[i], of[j], acc[i][j], 0, 0, 0);
        }
        __syncthreads();
    }

    // C: col = token (lcol within j-tile), row = out_n (quad*4 + r, consecutive)
    #pragma unroll
    for (int i = 0; i < 2; ++i) {
        int n4 = n0g + nb + i * 16 + quad * 4;
        float4 bv4 = *(const float4*)&bo[n4];
        #pragma unroll
        for (int j = 0; j < 4; ++j) {
            int token = m0g + j * 16 + lcol;
            float4 o;
            o.x = acc[i][j][0] + bv4.x;
            o.y = acc[i][j][1] + bv4.y;
            o.z = acc[i][j][2] + bv4.z;
            o.w = acc[i][j][3] + bv4.w;
            *(float4*)&out[(size_t)token * DD + n4] = o;
        }
    }
}

extern "C" void kernel_launch(void* const* d_in, const int* in_sizes, int n_in,
                              void* d_out, int out_size, void* d_ws, size_t ws_size,
                              hipStream_t stream)
{
    const float* x  = (const float*)d_in[0];
    const float* Wq = (const float*)d_in[1];
    const float* bq = (const float*)d_in[2];
    const float* Wk = (const float*)d_in[3];
    const float* bk = (const float*)d_in[4];
    const float* Wv = (const float*)d_in[5];
    const float* bv = (const float*)d_in[6];
    const float* Wo = (const float*)d_in[7];
    const float* bo = (const float*)d_in[8];
    float* out = (float*)d_out;

    unsigned short* ws = (unsigned short*)d_ws;
    unsigned short* Wt  = ws;                        // 4 * D*D (q,k,v,o)
    unsigned short* Wto = Wt + 3 * (size_t)DD * DD;
    unsigned short* Qb  = Wt + 4 * (size_t)DD * DD;  // M*D each
    unsigned short* Kb  = Qb + (size_t)MM * DD;
    unsigned short* Vt  = Kb + (size_t)MM * DD;
    unsigned short* xb  = Vt + (size_t)MM * DD;      // total 40 MB
    unsigned short* Ob  = xb;                        // alias: xb dead after qkv_gemm

    prep<<<8192, 256, 0, stream>>>(x, xb, Wq, Wk, Wv, Wo, Wt);

    qkv_gemm<<<dim3(8, 32, 3), 256, 0, stream>>>(xb, Wt, bq, bk, bv, Qb, Kb, Vt);

    attn<<<dim3(16, 32), 512, 0, stream>>>(Qb, Kb, Vt, Ob);

    out_gemm<<<dim3(DD / 128, MM / 64), 256, 0, stream>>>(Ob, Wto, bo, out);
}